// Round 7
// baseline (31642.545 us; speedup 1.0000x reference)
//
#include <hip/hip_runtime.h>
#include <hip/hip_bf16.h>

#define NATOMS 10000
#define NEDGES 320000
#define H 128
#define NRBF 50
#define NELEM (NATOMS * H)
#define NT 8192

typedef unsigned short u16;
typedef unsigned int u32;

__device__ __forceinline__ float bfu(u16 u) { return __uint_as_float(((u32)u) << 16); }
__device__ __forceinline__ float ldf(const void* p, int i, int bf) {
    return bf ? bfu(((const u16*)p)[i]) : ((const float*)p)[i];
}
__device__ __forceinline__ float silu_f(float v) { return v / (1.f + __expf(-v)); }
__device__ __forceinline__ float cutoff_f(float w) {
    float c = 0.5f * (__cosf(w * 0.62831853072f) + 1.f);
    return (w < 5.f) ? c : 0.f;
}
__device__ __forceinline__ float tlerp(const float* __restrict__ T, float w, int f) {
    float u = w * ((float)(NT - 1) / 5.0f);
    int ix = (int)u; ix = min(ix, NT - 2);
    float fr = u - (float)ix;
    float ta = T[ix * H + f], tb = T[ix * H + H + f];
    return fmaf(fr, tb - ta, ta);
}

// ---- dtype detect: means[49]==1.0 by construction.
__global__ void k_detect(const void* means, int* flag) {
    if (threadIdx.x == 0) {
        u32 w = ((const u32*)means)[24];
        *flag = ((w >> 16) == 0x3F80u) ? 1 : 0;
    }
}

__global__ __launch_bounds__(256) void k_embed(const int* __restrict__ z, const void* emb,
                                               float* __restrict__ x0, const int* flagp) {
    int bf = *flagp;
    int i = blockIdx.x * 256 + threadIdx.x;
    if (i < NELEM) {
        int n = i >> 7, f = i & 127;
        x0[i] = ldf(emb, z[n] * H + f, bf);
    }
}

__global__ __launch_bounds__(256) void k_store(const float* __restrict__ x, void* out,
                                               const int* flagp) {
    int bf = *flagp;
    int i = blockIdx.x * 256 + threadIdx.x;
    if (i < NELEM) {
        float v = x[i];
        if (bf) {
            u32 u = __float_as_uint(v);
            ((u16*)out)[i] = (u16)((u + 0x7FFFu + ((u >> 16) & 1u)) >> 16);
        } else {
            ((float*)out)[i] = v;
        }
    }
}

// ---- node GEMM, K=128 (proven) ----
__global__ __launch_bounds__(1024) void k_node_gemm(const float* __restrict__ in,
                                                    const void* W, int woff, int wstride,
                                                    const void* bias, float* __restrict__ out,
                                                    int mode, const int* flagp) {
    __shared__ __align__(16) float sW[H * 132];
    __shared__ __align__(16) float sIn[16][132];
    __shared__ float sB[H];
    int tid = threadIdx.x;
    int bf = *flagp;
    for (int i = tid; i < H * H; i += 1024) {
        int f2 = i >> 7, k = i & 127;
        sW[f2 * 132 + k] = ldf(W, woff + f2 * wstride + k, bf);
    }
    if (tid < H) sB[tid] = bias ? ldf(bias, tid, bf) : 0.f;
    __syncthreads();
    int g = tid >> 7, f = tid & 127;
    for (int base = blockIdx.x * 16; base < NATOMS; base += gridDim.x * 16) {
        int n0 = base + 2 * g, n1 = n0 + 1;
        sIn[2 * g][f] = in[n0 * H + f];
        sIn[2 * g + 1][f] = in[n1 * H + f];
        __syncthreads();
        float a0 = 0.f, a1 = 0.f;
        #pragma unroll
        for (int k = 0; k < H; k += 4) {
            float4 w4 = *(const float4*)&sW[f * 132 + k];
            float4 i0 = *(const float4*)&sIn[2 * g][k];
            float4 i1 = *(const float4*)&sIn[2 * g + 1][k];
            a0 = fmaf(w4.x, i0.x, a0); a0 = fmaf(w4.y, i0.y, a0);
            a0 = fmaf(w4.z, i0.z, a0); a0 = fmaf(w4.w, i0.w, a0);
            a1 = fmaf(w4.x, i1.x, a1); a1 = fmaf(w4.y, i1.y, a1);
            a1 = fmaf(w4.z, i1.z, a1); a1 = fmaf(w4.w, i1.w, a1);
        }
        float v0 = a0 + sB[f], v1 = a1 + sB[f];
        if (mode == 1) { v0 = silu_f(v0); v1 = silu_f(v1); }
        if (mode == 2) { out[n0 * H + f] += v0; out[n1 * H + f] += v1; }
        else           { out[n0 * H + f] = v0;  out[n1 * H + f] = v1; }
        __syncthreads();
    }
}

// ---- counting sort by src (proven rounds 4/5) ----
__global__ __launch_bounds__(256) void k_hist(const int* __restrict__ src, int* __restrict__ deg) {
    int e = blockIdx.x * 256 + threadIdx.x;
    if (e < NEDGES) atomicAdd(&deg[src[e]], 1);
}

__global__ __launch_bounds__(1024) void k_scan(const int* __restrict__ deg, int* __restrict__ rs) {
    __shared__ int buf[1024];
    __shared__ int carry;
    int tid = threadIdx.x;
    if (tid == 0) carry = 0;
    __syncthreads();
    for (int c = 0; c < 10; ++c) {
        int i = c * 1024 + tid;
        int v = (i < NATOMS) ? deg[i] : 0;
        buf[tid] = v;
        __syncthreads();
        for (int off = 1; off < 1024; off <<= 1) {
            int t = (tid >= off) ? buf[tid - off] : 0;
            __syncthreads();
            buf[tid] += t;
            __syncthreads();
        }
        int base = carry;
        if (i < NATOMS) rs[i] = base + buf[tid] - v;
        __syncthreads();
        if (tid == 0) carry = base + buf[1023];
        __syncthreads();
    }
}

__global__ __launch_bounds__(256) void k_scatter_perm(const int* __restrict__ src,
                                                      const int* __restrict__ dst,
                                                      const void* ew,
                                                      const int* __restrict__ rs,
                                                      int* __restrict__ cnt,
                                                      int* __restrict__ srcs,
                                                      int* __restrict__ dsts,
                                                      float* __restrict__ ews,
                                                      const int* flagp) {
    int e = blockIdx.x * 256 + threadIdx.x;
    if (e < NEDGES) {
        int s = src[e];
        int p = rs[s] + atomicAdd(&cnt[s], 1);
        srcs[p] = s;
        dsts[p] = dst[e];
        ews[p] = ldf(ew, e, *flagp);
    }
}

// ---- w-tables (proven)
// mode 1: T[i,f]=silu(C*g_f+b_f)   mode 0: T[i,f]=(C*g_f+b_f)*C
__global__ __launch_bounds__(256) void k_build_table(const void* means, const void* betas,
                                                     const void* W, int woff,
                                                     const void* B, int boff,
                                                     float* __restrict__ T, int mode,
                                                     const int* flagp) {
    __shared__ float sW[H * 52];
    __shared__ float sM[NRBF], sBe[NRBF];
    int tid = threadIdx.x;
    int bf = *flagp;
    for (int i = tid; i < H * NRBF; i += 256) {
        int f2 = i / NRBF, k = i - f2 * NRBF;
        sW[f2 * 52 + k] = ldf(W, woff + i, bf);
    }
    if (tid < NRBF) { sM[tid] = ldf(means, tid, bf); sBe[tid] = ldf(betas, tid, bf); }
    __syncthreads();
    int idx = blockIdx.x * 256 + tid;
    int i = idx >> 7, f = idx & 127;
    float w = (float)i * (5.0f / (NT - 1));
    float x = expf(-w);
    float c = 0.5f * (cosf(w * 0.62831853071795864f) + 1.f);
    if (!(w < 5.f)) c = 0.f;
    float g = 0.f;
    for (int k = 0; k < NRBF; ++k) {
        float t = x - sM[k];
        g += sW[f * 52 + k] * expf(-sBe[k] * t * t);
    }
    float b = ldf(B, boff + f, bf);
    float pre = c * g + b;
    T[i * H + f] = (mode == 1) ? silu_f(pre) : pre * c;
}

// ---- NE over sorted edges: run-accumulate, one atomic per src-run
__global__ __launch_bounds__(256) void k_ne_edge4(const int* __restrict__ srcs,
                                                  const int* __restrict__ dsts,
                                                  const float* __restrict__ ews,
                                                  const float* __restrict__ T,
                                                  const float* __restrict__ x0,
                                                  float* __restrict__ agg) {
    int tid = threadIdx.x;
    int g = tid >> 7, f = tid & 127;
    int gid = blockIdx.x * 2 + g;           // 2048 blocks -> 4096 groups x 80 edges
    int r0 = gid * 80;
    int rEnd = min(r0 + 80, NEDGES);
    int cur = -1; float racc = 0.f;
    for (int e = r0; e < rEnd; ++e) {       // bounds uniform per group
        int s = srcs[e], d = dsts[e];
        if (s == d) continue;
        float Wv = tlerp(T, ews[e], f);     // (C*g+b)*C baked in
        if (s != cur) {
            if (cur >= 0) atomicAdd(&agg[cur * H + f], racc);
            cur = s; racc = 0.f;
        }
        racc = fmaf(Wv, x0[d * H + f], racc);
    }
    if (cur >= 0) atomicAdd(&agg[cur * H + f], racc);
}

// ---- filter: sorted edges, 4 edges/macro-step, scalar-only state, run-flush
__global__ __launch_bounds__(1024) void k_edge_filter5(const int* __restrict__ srcs,
                                                       const int* __restrict__ dsts,
                                                       const float* __restrict__ ews,
                                                       const float* __restrict__ T,
                                                       const void* w1, int w1off,
                                                       const void* b1, int b1off,
                                                       const float* __restrict__ h,
                                                       float* __restrict__ out,
                                                       const int* flagp) {
    __shared__ __align__(16) float sW1[H * 132];
    __shared__ __align__(16) float sT[32][132];      // 8 groups x 4 edges
    int tid = threadIdx.x;
    int bf = *flagp;
    for (int i = tid; i < H * H; i += 1024) {
        int f2 = i >> 7, k = i & 127;
        sW1[f2 * 132 + k] = ldf(w1, w1off + i, bf);
    }
    int g = tid >> 7, f = tid & 127;
    float b1r = ldf(b1, b1off + f, bf);
    __syncthreads();
    int gid = blockIdx.x * 8 + g;                    // 256 blocks -> 2048 groups
    int r0 = gid * 160;
    int cur = -1; float racc = 0.f;
    for (int step = 0; step < 40; ++step) {
        int e0 = r0 + step * 4;
        bool v0 = (e0 + 0) < NEDGES, v1 = (e0 + 1) < NEDGES,
             v2 = (e0 + 2) < NEDGES, v3 = (e0 + 3) < NEDGES;
        float c0 = 0.f, c1 = 0.f, c2 = 0.f, c3 = 0.f;
        float t0v = 0.f, t1v = 0.f, t2v = 0.f, t3v = 0.f;
        if (v0) { float w = ews[e0 + 0]; c0 = cutoff_f(w); t0v = tlerp(T, w, f); }
        if (v1) { float w = ews[e0 + 1]; c1 = cutoff_f(w); t1v = tlerp(T, w, f); }
        if (v2) { float w = ews[e0 + 2]; c2 = cutoff_f(w); t2v = tlerp(T, w, f); }
        if (v3) { float w = ews[e0 + 3]; c3 = cutoff_f(w); t3v = tlerp(T, w, f); }
        sT[g * 4 + 0][f] = t0v;
        sT[g * 4 + 1][f] = t1v;
        sT[g * 4 + 2][f] = t2v;
        sT[g * 4 + 3][f] = t3v;
        __syncthreads();
        float A0 = 0.f, A1 = 0.f, A2 = 0.f, A3 = 0.f;
        #pragma unroll
        for (int k = 0; k < H; k += 4) {
            float4 wv = *(const float4*)&sW1[f * 132 + k];
            float4 q0 = *(const float4*)&sT[g * 4 + 0][k];
            float4 q1 = *(const float4*)&sT[g * 4 + 1][k];
            float4 q2 = *(const float4*)&sT[g * 4 + 2][k];
            float4 q3 = *(const float4*)&sT[g * 4 + 3][k];
            A0 = fmaf(wv.x, q0.x, A0); A0 = fmaf(wv.y, q0.y, A0);
            A0 = fmaf(wv.z, q0.z, A0); A0 = fmaf(wv.w, q0.w, A0);
            A1 = fmaf(wv.x, q1.x, A1); A1 = fmaf(wv.y, q1.y, A1);
            A1 = fmaf(wv.z, q1.z, A1); A1 = fmaf(wv.w, q1.w, A1);
            A2 = fmaf(wv.x, q2.x, A2); A2 = fmaf(wv.y, q2.y, A2);
            A2 = fmaf(wv.z, q2.z, A2); A2 = fmaf(wv.w, q2.w, A2);
            A3 = fmaf(wv.x, q3.x, A3); A3 = fmaf(wv.y, q3.y, A3);
            A3 = fmaf(wv.z, q3.z, A3); A3 = fmaf(wv.w, q3.w, A3);
        }
        __syncthreads();
        // epilogue: run-accumulate, scalars only (no local arrays!)
        if (v0) {
            int s = srcs[e0 + 0]; float vv = (A0 + b1r) * c0 * h[dsts[e0 + 0] * H + f];
            if (s != cur) { if (cur >= 0) atomicAdd(&out[cur * H + f], racc); cur = s; racc = 0.f; }
            racc += vv;
        }
        if (v1) {
            int s = srcs[e0 + 1]; float vv = (A1 + b1r) * c1 * h[dsts[e0 + 1] * H + f];
            if (s != cur) { if (cur >= 0) atomicAdd(&out[cur * H + f], racc); cur = s; racc = 0.f; }
            racc += vv;
        }
        if (v2) {
            int s = srcs[e0 + 2]; float vv = (A2 + b1r) * c2 * h[dsts[e0 + 2] * H + f];
            if (s != cur) { if (cur >= 0) atomicAdd(&out[cur * H + f], racc); cur = s; racc = 0.f; }
            racc += vv;
        }
        if (v3) {
            int s = srcs[e0 + 3]; float vv = (A3 + b1r) * c3 * h[dsts[e0 + 3] * H + f];
            if (s != cur) { if (cur >= 0) atomicAdd(&out[cur * H + f], racc); cur = s; racc = 0.f; }
            racc += vv;
        }
    }
    if (cur >= 0) atomicAdd(&out[cur * H + f], racc);
}

extern "C" void kernel_launch(void* const* d_in, const int* in_sizes, int n_in,
                              void* d_out, int out_size, void* d_ws, size_t ws_size,
                              hipStream_t stream) {
    const int* z  = (const int*)d_in[0];
    const int* ei = (const int*)d_in[1];
    const void* ew        = d_in[2];
    const void* emb       = d_in[3];
    const void* means     = d_in[4];
    const void* betas     = d_in[5];
    const void* ne_proj_w = d_in[6];
    const void* ne_proj_b = d_in[7];
    const void* ne_comb_w = d_in[8];
    const void* ne_comb_b = d_in[9];
    const void* mlp_w0    = d_in[10];
    const void* mlp_b0    = d_in[11];
    const void* mlp_w1    = d_in[12];
    const void* mlp_b1    = d_in[13];
    const void* lin1_w    = d_in[14];
    const void* lin2_w    = d_in[15];
    const void* lin2_b    = d_in[16];
    const void* lin_w     = d_in[17];
    const void* lin_b     = d_in[18];

    const int* srcp = ei;
    const int* dstp = ei + NEDGES;

    // layout (total 23.52 MB, same as round-4 fast path which ran => fits)
    float* buf0 = (float*)d_ws;            // x0, then h
    float* buf1 = buf0 + NELEM;            // scatter accumulator
    float* x    = buf1 + NELEM;            // persistent fp32 node state
    int*   flag = (int*)(x + NELEM);
    int*   deg  = flag + 16;
    int*   cnt  = deg + 10240;
    int*   rs   = cnt + 10240;
    int*   srcs = rs + 10240;
    int*   dsts = srcs + NEDGES;
    float* ews  = (float*)(dsts + NEDGES);
    float* T    = ews + NEDGES;            // 8192 x 128 fp32 (4.19 MB)

    const int gElem = (NELEM + 255) / 256;
    const int gEdge = (NEDGES + 255) / 256;

    k_detect<<<1, 64, 0, stream>>>(means, flag);
    k_embed<<<gElem, 256, 0, stream>>>(z, emb, buf0, flag);

    // counting sort by src
    hipMemsetAsync(deg, 0, 2 * 10240 * sizeof(int), stream);
    k_hist<<<gEdge, 256, 0, stream>>>(srcp, deg);
    k_scan<<<1, 1024, 0, stream>>>(deg, rs);
    k_scatter_perm<<<gEdge, 256, 0, stream>>>(srcp, dstp, ew, rs, cnt,
                                              srcs, dsts, ews, flag);

    // NeighborEmbedding
    hipMemsetAsync(buf1, 0, (size_t)NELEM * sizeof(float), stream);
    k_build_table<<<NT * H / 256, 256, 0, stream>>>(means, betas, ne_proj_w, 0,
                                                    ne_proj_b, 0, T, 0, flag);
    k_ne_edge4<<<2048, 256, 0, stream>>>(srcs, dsts, ews, T, buf0, buf1);
    k_node_gemm<<<512, 1024, 0, stream>>>(buf0, ne_comb_w, 0,   256, ne_comb_b, x, 0, flag);
    k_node_gemm<<<512, 1024, 0, stream>>>(buf1, ne_comb_w, 128, 256, nullptr,   x, 2, flag);

    for (int L = 0; L < 3; ++L) {
        k_node_gemm<<<512, 1024, 0, stream>>>(x, lin1_w, L * H * H, 128, nullptr, buf0, 0, flag);
        hipMemsetAsync(buf1, 0, (size_t)NELEM * sizeof(float), stream);
        k_build_table<<<NT * H / 256, 256, 0, stream>>>(means, betas, mlp_w0, L * H * NRBF,
                                                        mlp_b0, L * H, T, 1, flag);
        k_edge_filter5<<<256, 1024, 0, stream>>>(srcs, dsts, ews, T,
                                                 mlp_w1, L * H * H, mlp_b1, L * H,
                                                 buf0, buf1, flag);
        k_node_gemm<<<512, 1024, 0, stream>>>(buf1, lin2_w, L * H * H, 128, lin2_b, buf0, 1, flag);
        k_node_gemm<<<512, 1024, 0, stream>>>(buf0, lin_w,  L * H * H, 128, lin_b,  x,    2, flag);
    }

    k_store<<<gElem, 256, 0, stream>>>(x, d_out, flag);
}

// Round 8
// 1245.597 us; speedup vs baseline: 25.4035x; 25.4035x over previous
//
#include <hip/hip_runtime.h>
#include <hip/hip_bf16.h>

#define NATOMS 10000
#define NEDGES 320000
#define H 128
#define NRBF 50
#define NELEM (NATOMS * H)
#define NT 8192

typedef unsigned short u16;
typedef unsigned int u32;

__device__ __forceinline__ float bfu(u16 u) { return __uint_as_float(((u32)u) << 16); }
__device__ __forceinline__ float ldf(const void* p, int i, int bf) {
    return bf ? bfu(((const u16*)p)[i]) : ((const float*)p)[i];
}
__device__ __forceinline__ float silu_f(float v) { return v / (1.f + __expf(-v)); }
__device__ __forceinline__ float cutoff_f(float w) {
    float c = 0.5f * (__cosf(w * 0.62831853072f) + 1.f);
    return (w < 5.f) ? c : 0.f;
}
__device__ __forceinline__ float tlerp(const float* __restrict__ T, float w, int f) {
    float u = w * ((float)(NT - 1) / 5.0f);
    int ix = (int)u; ix = min(ix, NT - 2);
    float fr = u - (float)ix;
    float ta = T[ix * H + f], tb = T[ix * H + H + f];
    return fmaf(fr, tb - ta, ta);
}

// ---- dtype detect: means[49]==1.0 by construction.
__global__ void k_detect(const void* means, int* flag) {
    if (threadIdx.x == 0) {
        u32 w = ((const u32*)means)[24];
        *flag = ((w >> 16) == 0x3F80u) ? 1 : 0;
    }
}

__global__ __launch_bounds__(256) void k_embed(const int* __restrict__ z, const void* emb,
                                               float* __restrict__ x0, const int* flagp) {
    int bf = *flagp;
    int i = blockIdx.x * 256 + threadIdx.x;
    if (i < NELEM) {
        int n = i >> 7, f = i & 127;
        x0[i] = ldf(emb, z[n] * H + f, bf);
    }
}

__global__ __launch_bounds__(256) void k_store(const float* __restrict__ x, void* out,
                                               const int* flagp) {
    int bf = *flagp;
    int i = blockIdx.x * 256 + threadIdx.x;
    if (i < NELEM) {
        float v = x[i];
        if (bf) {
            u32 u = __float_as_uint(v);
            ((u16*)out)[i] = (u16)((u + 0x7FFFu + ((u >> 16) & 1u)) >> 16);
        } else {
            ((float*)out)[i] = v;
        }
    }
}

// ---- node GEMM, K=128 (proven rounds 3-6, unchanged) ----
__global__ __launch_bounds__(1024) void k_node_gemm(const float* __restrict__ in,
                                                    const void* W, int woff, int wstride,
                                                    const void* bias, float* __restrict__ out,
                                                    int mode, const int* flagp) {
    __shared__ __align__(16) float sW[H * 132];
    __shared__ __align__(16) float sIn[16][132];
    __shared__ float sB[H];
    int tid = threadIdx.x;
    int bf = *flagp;
    for (int i = tid; i < H * H; i += 1024) {
        int f2 = i >> 7, k = i & 127;
        sW[f2 * 132 + k] = ldf(W, woff + f2 * wstride + k, bf);
    }
    if (tid < H) sB[tid] = bias ? ldf(bias, tid, bf) : 0.f;
    __syncthreads();
    int g = tid >> 7, f = tid & 127;
    for (int base = blockIdx.x * 16; base < NATOMS; base += gridDim.x * 16) {
        int n0 = base + 2 * g, n1 = n0 + 1;
        sIn[2 * g][f] = in[n0 * H + f];
        sIn[2 * g + 1][f] = in[n1 * H + f];
        __syncthreads();
        float a0 = 0.f, a1 = 0.f;
        #pragma unroll
        for (int k = 0; k < H; k += 4) {
            float4 w4 = *(const float4*)&sW[f * 132 + k];
            float4 i0 = *(const float4*)&sIn[2 * g][k];
            float4 i1 = *(const float4*)&sIn[2 * g + 1][k];
            a0 = fmaf(w4.x, i0.x, a0); a0 = fmaf(w4.y, i0.y, a0);
            a0 = fmaf(w4.z, i0.z, a0); a0 = fmaf(w4.w, i0.w, a0);
            a1 = fmaf(w4.x, i1.x, a1); a1 = fmaf(w4.y, i1.y, a1);
            a1 = fmaf(w4.z, i1.z, a1); a1 = fmaf(w4.w, i1.w, a1);
        }
        float v0 = a0 + sB[f], v1 = a1 + sB[f];
        if (mode == 1) { v0 = silu_f(v0); v1 = silu_f(v1); }
        if (mode == 2) { out[n0 * H + f] += v0; out[n1 * H + f] += v1; }
        else           { out[n0 * H + f] = v0;  out[n1 * H + f] = v1; }
        __syncthreads();
    }
}

// ---- table GEMM: T[i,:] <- (T[i,:] @ w1.T + b1) * C(w_i), in-place, 8192 rows.
// Same proven codegen shape as k_node_gemm (in-place safe: each block reads its
// rows into LDS before overwriting them; rows are block-private).
__global__ __launch_bounds__(1024) void k_table_gemm(float* __restrict__ T,
                                                     const void* W, int woff,
                                                     const void* bias, int boff,
                                                     const int* flagp) {
    __shared__ __align__(16) float sW[H * 132];
    __shared__ __align__(16) float sIn[16][132];
    __shared__ float sB[H];
    int tid = threadIdx.x;
    int bf = *flagp;
    for (int i = tid; i < H * H; i += 1024) {
        int f2 = i >> 7, k = i & 127;
        sW[f2 * 132 + k] = ldf(W, woff + f2 * H + k, bf);
    }
    if (tid < H) sB[tid] = ldf(bias, boff + tid, bf);
    __syncthreads();
    int g = tid >> 7, f = tid & 127;
    for (int base = blockIdx.x * 16; base < NT; base += gridDim.x * 16) {
        int n0 = base + 2 * g, n1 = n0 + 1;       // NT % 16 == 0
        sIn[2 * g][f] = T[n0 * H + f];
        sIn[2 * g + 1][f] = T[n1 * H + f];
        __syncthreads();
        float a0 = 0.f, a1 = 0.f;
        #pragma unroll
        for (int k = 0; k < H; k += 4) {
            float4 w4 = *(const float4*)&sW[f * 132 + k];
            float4 i0 = *(const float4*)&sIn[2 * g][k];
            float4 i1 = *(const float4*)&sIn[2 * g + 1][k];
            a0 = fmaf(w4.x, i0.x, a0); a0 = fmaf(w4.y, i0.y, a0);
            a0 = fmaf(w4.z, i0.z, a0); a0 = fmaf(w4.w, i0.w, a0);
            a1 = fmaf(w4.x, i1.x, a1); a1 = fmaf(w4.y, i1.y, a1);
            a1 = fmaf(w4.z, i1.z, a1); a1 = fmaf(w4.w, i1.w, a1);
        }
        float w0v = (float)n0 * (5.0f / (NT - 1));
        float w1v = (float)n1 * (5.0f / (NT - 1));
        float v0 = (a0 + sB[f]) * cutoff_f(w0v);
        float v1 = (a1 + sB[f]) * cutoff_f(w1v);
        T[n0 * H + f] = v0;
        T[n1 * H + f] = v1;
        __syncthreads();
    }
}

// ---- w-tables (proven)
// mode 1: T[i,f]=silu(C*g_f+b_f)   mode 0: T[i,f]=(C*g_f+b_f)*C
__global__ __launch_bounds__(256) void k_build_table(const void* means, const void* betas,
                                                     const void* W, int woff,
                                                     const void* B, int boff,
                                                     float* __restrict__ T, int mode,
                                                     const int* flagp) {
    __shared__ float sW[H * 52];
    __shared__ float sM[NRBF], sBe[NRBF];
    int tid = threadIdx.x;
    int bf = *flagp;
    for (int i = tid; i < H * NRBF; i += 256) {
        int f2 = i / NRBF, k = i - f2 * NRBF;
        sW[f2 * 52 + k] = ldf(W, woff + i, bf);
    }
    if (tid < NRBF) { sM[tid] = ldf(means, tid, bf); sBe[tid] = ldf(betas, tid, bf); }
    __syncthreads();
    int idx = blockIdx.x * 256 + tid;
    int i = idx >> 7, f = idx & 127;
    float w = (float)i * (5.0f / (NT - 1));
    float x = expf(-w);
    float c = 0.5f * (cosf(w * 0.62831853071795864f) + 1.f);
    if (!(w < 5.f)) c = 0.f;
    float g = 0.f;
    for (int k = 0; k < NRBF; ++k) {
        float t = x - sM[k];
        g += sW[f * 52 + k] * expf(-sBe[k] * t * t);
    }
    float b = ldf(B, boff + f, bf);
    float pre = c * g + b;
    T[i * H + f] = (mode == 1) ? silu_f(pre) : pre * c;
}

// ---- edge apply (round-6-proven k_ne_edge3 shape, parameterized self-mask):
// acc[src] += tlerp(T, w_e) * vin[dst]   — no LDS, no barriers, per-edge atomics
__global__ __launch_bounds__(256) void k_edge_apply(const int* __restrict__ src,
                                                    const int* __restrict__ dst,
                                                    const void* ew,
                                                    const float* __restrict__ T,
                                                    const float* __restrict__ vin,
                                                    float* __restrict__ acc,
                                                    const int* flagp, int mask_self) {
    int bf = *flagp;
    int tid = threadIdx.x;
    int g = tid >> 7, f = tid & 127;
    for (int e = blockIdx.x * 2 + g; e < NEDGES; e += gridDim.x * 2) {
        int s = src[e], d = dst[e];
        if (mask_self && s == d) continue;
        float w = ldf(ew, e, bf);
        float Wv = tlerp(T, w, f);
        atomicAdd(&acc[s * H + f], Wv * vin[d * H + f]);
    }
}

extern "C" void kernel_launch(void* const* d_in, const int* in_sizes, int n_in,
                              void* d_out, int out_size, void* d_ws, size_t ws_size,
                              hipStream_t stream) {
    const int* z  = (const int*)d_in[0];
    const int* ei = (const int*)d_in[1];
    const void* ew        = d_in[2];
    const void* emb       = d_in[3];
    const void* means     = d_in[4];
    const void* betas     = d_in[5];
    const void* ne_proj_w = d_in[6];
    const void* ne_proj_b = d_in[7];
    const void* ne_comb_w = d_in[8];
    const void* ne_comb_b = d_in[9];
    const void* mlp_w0    = d_in[10];
    const void* mlp_b0    = d_in[11];
    const void* mlp_w1    = d_in[12];
    const void* mlp_b1    = d_in[13];
    const void* lin1_w    = d_in[14];
    const void* lin2_w    = d_in[15];
    const void* lin2_b    = d_in[16];
    const void* lin_w     = d_in[17];
    const void* lin_b     = d_in[18];

    const int* srcp = ei;
    const int* dstp = ei + NEDGES;

    float* buf0 = (float*)d_ws;            // x0, then h
    float* buf1 = buf0 + NELEM;            // scatter accumulator
    float* x    = buf1 + NELEM;            // persistent fp32 node state
    int*   flag = (int*)(x + NELEM);
    float* T    = (float*)(flag + 16);     // 8192 x 128 fp32 table (4.19 MB)

    const int gElem = (NELEM + 255) / 256;

    k_detect<<<1, 64, 0, stream>>>(means, flag);
    k_embed<<<gElem, 256, 0, stream>>>(z, emb, buf0, flag);

    // NeighborEmbedding: fully-baked table, then pure table-apply edges
    hipMemsetAsync(buf1, 0, (size_t)NELEM * sizeof(float), stream);
    k_build_table<<<NT * H / 256, 256, 0, stream>>>(means, betas, ne_proj_w, 0,
                                                    ne_proj_b, 0, T, 0, flag);
    k_edge_apply<<<2048, 256, 0, stream>>>(srcp, dstp, ew, T, buf0, buf1, flag, 1);
    k_node_gemm<<<512, 1024, 0, stream>>>(buf0, ne_comb_w, 0,   256, ne_comb_b, x, 0, flag);
    k_node_gemm<<<512, 1024, 0, stream>>>(buf1, ne_comb_w, 128, 256, nullptr,   x, 2, flag);

    for (int L = 0; L < 3; ++L) {
        // h = x @ l1w.T
        k_node_gemm<<<512, 1024, 0, stream>>>(x, lin1_w, L * H * H, 128, nullptr, buf0, 0, flag);
        hipMemsetAsync(buf1, 0, (size_t)NELEM * sizeof(float), stream);
        // full filter table: T = silu-row table, then T <- (T @ w1.T + b1)*C in-place
        k_build_table<<<NT * H / 256, 256, 0, stream>>>(means, betas, mlp_w0, L * H * NRBF,
                                                        mlp_b0, L * H, T, 1, flag);
        k_table_gemm<<<512, 1024, 0, stream>>>(T, mlp_w1, L * H * H, mlp_b1, L * H, flag);
        // edge pass: a[src] += T(w) ⊙ h[dst]  (no self mask)
        k_edge_apply<<<2048, 256, 0, stream>>>(srcp, dstp, ew, T, buf0, buf1, flag, 0);
        // h = silu(a @ l2w.T + b2);  x += h @ lw.T + lb
        k_node_gemm<<<512, 1024, 0, stream>>>(buf1, lin2_w, L * H * H, 128, lin2_b, buf0, 1, flag);
        k_node_gemm<<<512, 1024, 0, stream>>>(buf0, lin_w,  L * H * H, 128, lin_b,  x,    2, flag);
    }

    k_store<<<gElem, 256, 0, stream>>>(x, d_out, flag);
}